// Round 15
// baseline (65.035 us; speedup 1.0000x reference)
//
#include <hip/hip_runtime.h>

#define B 4
#define N 1024
#define K 100
#define F 42
#define H 64

#define PAIRS (K * F)          // 4200
#define MF4   (PAIRS * 3 / 4)  // 3150 f32x4 of dfeat per atom
#define QP    (PAIRS / 4)      // 1050 quad-pairs per atom

#define APW 2                  // mlp: atoms per wave
#define NWV 8                  // mlp: waves per block -> 2 waves/SIMD
#define APB (APW * NWV)        // 16 atoms/block -> grid 256 (1 block/CU)
#define BT  (NWV * 64)         // 512 threads
#define PW  68
#define PX  44

typedef float f32x4 __attribute__((ext_vector_type(4)));

// ---------------------------------------------------------------------------
// Kernel 1 (v13, byte-identical to R13 best): MLP fwd + input grad.
// MEASUREMENT ROUND: launched 4x (idempotent, deterministic) to decompose
// total = force + 4*mlp + gaps and pin where the ~11 us residual lives.
// ---------------------------------------------------------------------------
__global__ __launch_bounds__(BT) void mlp_kernel(
    const float* __restrict__ image,
    const float* __restrict__ W1, const float* __restrict__ b1,
    const float* __restrict__ W2, const float* __restrict__ b2,
    const float* __restrict__ W3, const float* __restrict__ b3,
    float* __restrict__ Ei, float* __restrict__ dE)
{
    __shared__ __align__(16) float W1s[F][PW];
    __shared__ __align__(16) float W2s[H][PW];
    __shared__ __align__(16) float xsh[APB][PX];
    __shared__ __align__(16) float h1sh[NWV][APW][H];
    __shared__ __align__(16) float g2sh[NWV][APW][H];
    __shared__ __align__(16) float g1sh[NWV][APW][H];

    const int tid  = threadIdx.x;
    const int lane = tid & 63;
    const int wv   = tid >> 6;          // 0..7
    const int a0   = blockIdx.x * APB;
    const int aw   = a0 + wv * APW;

    for (int idx = tid; idx < F * H; idx += BT)
        W1s[idx >> 6][idx & 63] = W1[idx];
    for (int idx = tid; idx < H * H; idx += BT)
        W2s[idx >> 6][idx & 63] = W2[idx];
    for (int idx = tid; idx < APB * F; idx += BT) {
        const int a = idx / F, f = idx - a * F;
        xsh[a][f] = image[(size_t)a0 * F + idx];
    }
    __syncthreads();

    float acc[APW];
    {
        const float bb = b1[lane];
        #pragma unroll
        for (int a = 0; a < APW; ++a) acc[a] = bb;
    }
    #pragma unroll
    for (int fc = 0; fc < 10; ++fc) {
        float wv4[4];
        #pragma unroll
        for (int t = 0; t < 4; ++t) wv4[t] = W1s[4 * fc + t][lane];
        #pragma unroll
        for (int a = 0; a < APW; ++a) {
            const f32x4 xv = *(const f32x4*)&xsh[wv * APW + a][4 * fc];
            #pragma unroll
            for (int t = 0; t < 4; ++t) acc[a] = fmaf(xv[t], wv4[t], acc[a]);
        }
    }
    #pragma unroll
    for (int f = 40; f < F; ++f) {
        const float w = W1s[f][lane];
        #pragma unroll
        for (int a = 0; a < APW; ++a) acc[a] = fmaf(xsh[wv * APW + a][f], w, acc[a]);
    }
    float h1l[APW];
    #pragma unroll
    for (int a = 0; a < APW; ++a) {
        h1l[a] = tanhf(acc[a]);
        h1sh[wv][a][lane] = h1l[a];
    }
    __builtin_amdgcn_wave_barrier();

    {
        const float bb = b2[lane];
        #pragma unroll
        for (int a = 0; a < APW; ++a) acc[a] = bb;
    }
    #pragma unroll
    for (int jc = 0; jc < H / 4; ++jc) {
        float wv4[4];
        #pragma unroll
        for (int t = 0; t < 4; ++t) wv4[t] = W2s[4 * jc + t][lane];
        #pragma unroll
        for (int a = 0; a < APW; ++a) {
            const f32x4 hv = *(const f32x4*)&h1sh[wv][a][4 * jc];
            #pragma unroll
            for (int t = 0; t < 4; ++t) acc[a] = fmaf(hv[t], wv4[t], acc[a]);
        }
    }
    const float w3    = W3[lane];
    const float bias3 = b3[0];
    #pragma unroll
    for (int a = 0; a < APW; ++a) {
        const float h2 = tanhf(acc[a]);
        g2sh[wv][a][lane] = w3 * (1.0f - h2 * h2);
        float t = h2 * w3;
        #pragma unroll
        for (int off = 32; off > 0; off >>= 1) t += __shfl_down(t, off);
        if (lane == 0) Ei[aw + a] = t + bias3;
    }
    __builtin_amdgcn_wave_barrier();

    float s[APW];
    #pragma unroll
    for (int a = 0; a < APW; ++a) s[a] = 0.0f;
    #pragma unroll
    for (int ic = 0; ic < H / 4; ++ic) {
        const f32x4 wr = *(const f32x4*)&W2s[lane][4 * ic];
        #pragma unroll
        for (int a = 0; a < APW; ++a) {
            const f32x4 gv = *(const f32x4*)&g2sh[wv][a][4 * ic];
            #pragma unroll
            for (int t = 0; t < 4; ++t) s[a] = fmaf(wr[t], gv[t], s[a]);
        }
    }
    #pragma unroll
    for (int a = 0; a < APW; ++a)
        g1sh[wv][a][lane] = s[a] * (1.0f - h1l[a] * h1l[a]);
    __builtin_amdgcn_wave_barrier();

    if (lane < F) {
        float dx[APW];
        #pragma unroll
        for (int a = 0; a < APW; ++a) dx[a] = 0.0f;
        #pragma unroll
        for (int ic = 0; ic < H / 4; ++ic) {
            const f32x4 wr = *(const f32x4*)&W1s[lane][4 * ic];
            #pragma unroll
            for (int a = 0; a < APW; ++a) {
                const f32x4 gv = *(const f32x4*)&g1sh[wv][a][4 * ic];
                #pragma unroll
                for (int t = 0; t < 4; ++t) dx[a] = fmaf(wr[t], gv[t], dx[a]);
            }
        }
        #pragma unroll
        for (int a = 0; a < APW; ++a)
            dE[(size_t)(aw + a) * F + lane] = dx[a];
    }
}

// ---------------------------------------------------------------------------
// Kernel 2 (R9, byte-identical): Force + Etot tail blocks.
// ---------------------------------------------------------------------------
__global__ __launch_bounds__(256) void force_kernel(
    const float* __restrict__ dE, const float* __restrict__ dfeat,
    const int* __restrict__ neighbor, const float* __restrict__ Ei,
    float* __restrict__ force, float* __restrict__ Etot)
{
    __shared__ int   nsh[K];
    __shared__ float red[4][3];

    const int tid  = threadIdx.x;
    const int bid  = blockIdx.x;
    const int lane = tid & 63, wave = tid >> 6;

    if (bid >= B * N) {                    // ---- Etot tail blocks ----
        const int b = bid - B * N;
        float s = 0.0f;
        for (int i = tid; i < N; i += 256) s += Ei[b * N + i];
        #pragma unroll
        for (int off = 32; off > 0; off >>= 1) s += __shfl_down(s, off);
        if (lane == 0) red[wave][0] = s;
        __syncthreads();
        if (tid == 0)
            Etot[b] = (red[0][0] + red[1][0]) + (red[2][0] + red[3][0]);
        return;
    }

    const int bn = bid;
    const int b  = bn >> 10;               // N = 1024

    if (tid < K) nsh[tid] = neighbor[bn * K + tid];
    __syncthreads();

    const f32x4* df4 = (const f32x4*)dfeat + (size_t)bn * MF4;
    const float* dEb = dE + (size_t)b * (N * F);

    float fx = 0.0f, fy = 0.0f, fz = 0.0f;

    #pragma unroll 1
    for (int it = 0; it < 4; ++it) {       // full iters: quad-pairs 0..1023
        const int p4 = it * 256 + tid;
        const int p  = 4 * p4;
        const f32x4 d0 = df4[3 * p4 + 0];
        const f32x4 d1 = df4[3 * p4 + 1];
        const f32x4 d2 = df4[3 * p4 + 2];
        float e[4];
        #pragma unroll
        for (int q = 0; q < 4; ++q) {
            const int pp = p + q;
            const int k  = pp / F;
            const int f  = pp - k * F;
            const int nb = nsh[k];
            e[q] = (nb > 0) ? dEb[(nb - 1) * F + f] : 0.0f;
        }
        fx = fmaf(e[0], d0.x, fx); fy = fmaf(e[0], d0.y, fy); fz = fmaf(e[0], d0.z, fz);
        fx = fmaf(e[1], d0.w, fx); fy = fmaf(e[1], d1.x, fy); fz = fmaf(e[1], d1.y, fz);
        fx = fmaf(e[2], d1.z, fx); fy = fmaf(e[2], d1.w, fy); fz = fmaf(e[2], d2.x, fz);
        fx = fmaf(e[3], d2.y, fx); fy = fmaf(e[3], d2.z, fy); fz = fmaf(e[3], d2.w, fz);
    }
    if (tid < QP - 1024) {                 // tail: quad-pairs 1024..1049
        const int p4 = 1024 + tid;
        const int p  = 4 * p4;
        const f32x4 d0 = df4[3 * p4 + 0];
        const f32x4 d1 = df4[3 * p4 + 1];
        const f32x4 d2 = df4[3 * p4 + 2];
        float e[4];
        #pragma unroll
        for (int q = 0; q < 4; ++q) {
            const int pp = p + q;
            const int k  = pp / F;
            const int f  = pp - k * F;
            const int nb = nsh[k];
            e[q] = (nb > 0) ? dEb[(nb - 1) * F + f] : 0.0f;
        }
        fx = fmaf(e[0], d0.x, fx); fy = fmaf(e[0], d0.y, fy); fz = fmaf(e[0], d0.z, fz);
        fx = fmaf(e[1], d0.w, fx); fy = fmaf(e[1], d1.x, fy); fz = fmaf(e[1], d1.y, fz);
        fx = fmaf(e[2], d1.z, fx); fy = fmaf(e[2], d1.w, fy); fz = fmaf(e[2], d2.x, fz);
        fx = fmaf(e[3], d2.y, fx); fy = fmaf(e[3], d2.z, fy); fz = fmaf(e[3], d2.w, fz);
    }

    #pragma unroll
    for (int off = 32; off > 0; off >>= 1) {
        fx += __shfl_down(fx, off);
        fy += __shfl_down(fy, off);
        fz += __shfl_down(fz, off);
    }
    if (lane == 0) { red[wave][0] = fx; red[wave][1] = fy; red[wave][2] = fz; }
    __syncthreads();
    if (tid == 0) {
        force[bn * 3 + 0] = (red[0][0] + red[1][0]) + (red[2][0] + red[3][0]);
        force[bn * 3 + 1] = (red[0][1] + red[1][1]) + (red[2][1] + red[3][1]);
        force[bn * 3 + 2] = (red[0][2] + red[1][2]) + (red[2][2] + red[3][2]);
    }
}

extern "C" void kernel_launch(void* const* d_in, const int* in_sizes, int n_in,
                              void* d_out, int out_size, void* d_ws, size_t ws_size,
                              hipStream_t stream)
{
    const float* image    = (const float*)d_in[0];
    const float* dfeat    = (const float*)d_in[1];
    const int*   neighbor = (const int*)d_in[2];
    // d_in[3] Egroup_weight, d_in[4] divider: unused by the reference outputs
    const float* W1 = (const float*)d_in[5];
    const float* b1 = (const float*)d_in[6];
    const float* W2 = (const float*)d_in[7];
    const float* b2 = (const float*)d_in[8];
    const float* W3 = (const float*)d_in[9];
    const float* b3 = (const float*)d_in[10];

    float* out   = (float*)d_out;
    float* Etot  = out;                 // [B]
    float* Ei    = out + B;             // [B,N]
    float* Force = out + B + B * N;     // [B,N,3]
    float* dE    = (float*)d_ws;        // [B,N,F]

    // MEASUREMENT: 4 idempotent mlp launches (identical outputs each time).
    // total = 4*mlp + force + gaps  ->  solves for mlp kernel time.
    for (int rep = 0; rep < 4; ++rep)
        mlp_kernel<<<(B * N) / APB, BT, 0, stream>>>(image, W1, b1, W2, b2, W3, b3, Ei, dE);
    force_kernel<<<B * N + B, 256, 0, stream>>>(dE, dfeat, neighbor, Ei, Force, Etot);
}

// Round 16
// 45.382 us; speedup vs baseline: 1.4331x; 1.4331x over previous
//
#include <hip/hip_runtime.h>

#define B 4
#define N 1024
#define K 100
#define F 42
#define H 64

#define PAIRS (K * F)          // 4200
#define MF4   (PAIRS * 3 / 4)  // 3150 f32x4 of dfeat per atom
#define QP    (PAIRS / 4)      // 1050 quad-pairs per atom

#define APW 1                  // mlp: atoms per wave (was 2) -> half the chain
#define NWV 8                  // mlp: waves per block
#define APB (APW * NWV)        // 8 atoms/block -> grid 512 -> 2 blocks/CU
#define BT  (NWV * 64)         // 512 threads
#define PW  68
#define PX  44

typedef float f32x4 __attribute__((ext_vector_type(4)));

// ---------------------------------------------------------------------------
// Kernel 1 (v15 = v13 @ APW=1): MLP fwd + input grad. lane = hidden unit,
// wave = 1 atom, 8 waves/block, grid 512 (2 blocks/CU -> 4 waves/SIMD).
// R15 measurement showed mlp is dependency-stall bound, not pipe-bound:
// halve the serial chain AND double TLP.
// ---------------------------------------------------------------------------
__global__ __launch_bounds__(BT) void mlp_kernel(
    const float* __restrict__ image,
    const float* __restrict__ W1, const float* __restrict__ b1,
    const float* __restrict__ W2, const float* __restrict__ b2,
    const float* __restrict__ W3, const float* __restrict__ b3,
    float* __restrict__ Ei, float* __restrict__ dE)
{
    __shared__ __align__(16) float W1s[F][PW];
    __shared__ __align__(16) float W2s[H][PW];
    __shared__ __align__(16) float xsh[APB][PX];
    __shared__ __align__(16) float h1sh[NWV][H];
    __shared__ __align__(16) float g2sh[NWV][H];
    __shared__ __align__(16) float g1sh[NWV][H];

    const int tid  = threadIdx.x;
    const int lane = tid & 63;
    const int wv   = tid >> 6;          // 0..7
    const int a0   = blockIdx.x * APB;
    const int atom = a0 + wv;

    for (int idx = tid; idx < F * H; idx += BT)
        W1s[idx >> 6][idx & 63] = W1[idx];
    for (int idx = tid; idx < H * H; idx += BT)
        W2s[idx >> 6][idx & 63] = W2[idx];
    for (int idx = tid; idx < APB * F; idx += BT) {
        const int a = idx / F, f = idx - a * F;
        xsh[a][f] = image[(size_t)a0 * F + idx];
    }
    __syncthreads();

    // ---- layer 1: acc = b1 + sum_f x[f] * W1[f][lane] ----
    float acc = b1[lane];
    #pragma unroll
    for (int fc = 0; fc < 10; ++fc) {
        float wv4[4];
        #pragma unroll
        for (int t = 0; t < 4; ++t) wv4[t] = W1s[4 * fc + t][lane];
        const f32x4 xv = *(const f32x4*)&xsh[wv][4 * fc];
        #pragma unroll
        for (int t = 0; t < 4; ++t) acc = fmaf(xv[t], wv4[t], acc);
    }
    #pragma unroll
    for (int f = 40; f < F; ++f)
        acc = fmaf(xsh[wv][f], W1s[f][lane], acc);
    const float h1 = tanhf(acc);
    h1sh[wv][lane] = h1;
    __builtin_amdgcn_wave_barrier();

    // ---- layer 2: b2 + sum_j h1[j] * W2[j][lane] ----
    float a2 = b2[lane];
    #pragma unroll
    for (int jc = 0; jc < H / 4; ++jc) {
        float wv4[4];
        #pragma unroll
        for (int t = 0; t < 4; ++t) wv4[t] = W2s[4 * jc + t][lane];
        const f32x4 hv = *(const f32x4*)&h1sh[wv][4 * jc];
        #pragma unroll
        for (int t = 0; t < 4; ++t) a2 = fmaf(hv[t], wv4[t], a2);
    }
    const float w3    = W3[lane];
    const float bias3 = b3[0];
    const float h2    = tanhf(a2);
    g2sh[wv][lane] = w3 * (1.0f - h2 * h2);
    {
        float t = h2 * w3;
        #pragma unroll
        for (int off = 32; off > 0; off >>= 1) t += __shfl_down(t, off);
        if (lane == 0) Ei[atom] = t + bias3;
    }
    __builtin_amdgcn_wave_barrier();

    // ---- g1[lane] = (1-h1^2) * sum_i W2[lane][i] * g2[i] ----
    float s = 0.0f;
    #pragma unroll
    for (int ic = 0; ic < H / 4; ++ic) {
        const f32x4 wr = *(const f32x4*)&W2s[lane][4 * ic];
        const f32x4 gv = *(const f32x4*)&g2sh[wv][4 * ic];
        #pragma unroll
        for (int t = 0; t < 4; ++t) s = fmaf(wr[t], gv[t], s);
    }
    g1sh[wv][lane] = s * (1.0f - h1 * h1);
    __builtin_amdgcn_wave_barrier();

    // ---- dE[f=lane] = sum_i W1[lane][i] * g1[i] ----
    if (lane < F) {
        float dx = 0.0f;
        #pragma unroll
        for (int ic = 0; ic < H / 4; ++ic) {
            const f32x4 wr = *(const f32x4*)&W1s[lane][4 * ic];
            const f32x4 gv = *(const f32x4*)&g1sh[wv][4 * ic];
            #pragma unroll
            for (int t = 0; t < 4; ++t) dx = fmaf(wr[t], gv[t], dx);
        }
        dE[(size_t)atom * F + lane] = dx;
    }
}

// ---------------------------------------------------------------------------
// Kernel 2 (R9, byte-identical): Force + Etot tail blocks.
// ---------------------------------------------------------------------------
__global__ __launch_bounds__(256) void force_kernel(
    const float* __restrict__ dE, const float* __restrict__ dfeat,
    const int* __restrict__ neighbor, const float* __restrict__ Ei,
    float* __restrict__ force, float* __restrict__ Etot)
{
    __shared__ int   nsh[K];
    __shared__ float red[4][3];

    const int tid  = threadIdx.x;
    const int bid  = blockIdx.x;
    const int lane = tid & 63, wave = tid >> 6;

    if (bid >= B * N) {                    // ---- Etot tail blocks ----
        const int b = bid - B * N;
        float s = 0.0f;
        for (int i = tid; i < N; i += 256) s += Ei[b * N + i];
        #pragma unroll
        for (int off = 32; off > 0; off >>= 1) s += __shfl_down(s, off);
        if (lane == 0) red[wave][0] = s;
        __syncthreads();
        if (tid == 0)
            Etot[b] = (red[0][0] + red[1][0]) + (red[2][0] + red[3][0]);
        return;
    }

    const int bn = bid;
    const int b  = bn >> 10;               // N = 1024

    if (tid < K) nsh[tid] = neighbor[bn * K + tid];
    __syncthreads();

    const f32x4* df4 = (const f32x4*)dfeat + (size_t)bn * MF4;
    const float* dEb = dE + (size_t)b * (N * F);

    float fx = 0.0f, fy = 0.0f, fz = 0.0f;

    #pragma unroll 1
    for (int it = 0; it < 4; ++it) {       // full iters: quad-pairs 0..1023
        const int p4 = it * 256 + tid;
        const int p  = 4 * p4;
        const f32x4 d0 = df4[3 * p4 + 0];
        const f32x4 d1 = df4[3 * p4 + 1];
        const f32x4 d2 = df4[3 * p4 + 2];
        float e[4];
        #pragma unroll
        for (int q = 0; q < 4; ++q) {
            const int pp = p + q;
            const int k  = pp / F;
            const int f  = pp - k * F;
            const int nb = nsh[k];
            e[q] = (nb > 0) ? dEb[(nb - 1) * F + f] : 0.0f;
        }
        fx = fmaf(e[0], d0.x, fx); fy = fmaf(e[0], d0.y, fy); fz = fmaf(e[0], d0.z, fz);
        fx = fmaf(e[1], d0.w, fx); fy = fmaf(e[1], d1.x, fy); fz = fmaf(e[1], d1.y, fz);
        fx = fmaf(e[2], d1.z, fx); fy = fmaf(e[2], d1.w, fy); fz = fmaf(e[2], d2.x, fz);
        fx = fmaf(e[3], d2.y, fx); fy = fmaf(e[3], d2.z, fy); fz = fmaf(e[3], d2.w, fz);
    }
    if (tid < QP - 1024) {                 // tail: quad-pairs 1024..1049
        const int p4 = 1024 + tid;
        const int p  = 4 * p4;
        const f32x4 d0 = df4[3 * p4 + 0];
        const f32x4 d1 = df4[3 * p4 + 1];
        const f32x4 d2 = df4[3 * p4 + 2];
        float e[4];
        #pragma unroll
        for (int q = 0; q < 4; ++q) {
            const int pp = p + q;
            const int k  = pp / F;
            const int f  = pp - k * F;
            const int nb = nsh[k];
            e[q] = (nb > 0) ? dEb[(nb - 1) * F + f] : 0.0f;
        }
        fx = fmaf(e[0], d0.x, fx); fy = fmaf(e[0], d0.y, fy); fz = fmaf(e[0], d0.z, fz);
        fx = fmaf(e[1], d0.w, fx); fy = fmaf(e[1], d1.x, fy); fz = fmaf(e[1], d1.y, fz);
        fx = fmaf(e[2], d1.z, fx); fy = fmaf(e[2], d1.w, fy); fz = fmaf(e[2], d2.x, fz);
        fx = fmaf(e[3], d2.y, fx); fy = fmaf(e[3], d2.z, fy); fz = fmaf(e[3], d2.w, fz);
    }

    #pragma unroll
    for (int off = 32; off > 0; off >>= 1) {
        fx += __shfl_down(fx, off);
        fy += __shfl_down(fy, off);
        fz += __shfl_down(fz, off);
    }
    if (lane == 0) { red[wave][0] = fx; red[wave][1] = fy; red[wave][2] = fz; }
    __syncthreads();
    if (tid == 0) {
        force[bn * 3 + 0] = (red[0][0] + red[1][0]) + (red[2][0] + red[3][0]);
        force[bn * 3 + 1] = (red[0][1] + red[1][1]) + (red[2][1] + red[3][1]);
        force[bn * 3 + 2] = (red[0][2] + red[1][2]) + (red[2][2] + red[3][2]);
    }
}

extern "C" void kernel_launch(void* const* d_in, const int* in_sizes, int n_in,
                              void* d_out, int out_size, void* d_ws, size_t ws_size,
                              hipStream_t stream)
{
    const float* image    = (const float*)d_in[0];
    const float* dfeat    = (const float*)d_in[1];
    const int*   neighbor = (const int*)d_in[2];
    // d_in[3] Egroup_weight, d_in[4] divider: unused by the reference outputs
    const float* W1 = (const float*)d_in[5];
    const float* b1 = (const float*)d_in[6];
    const float* W2 = (const float*)d_in[7];
    const float* b2 = (const float*)d_in[8];
    const float* W3 = (const float*)d_in[9];
    const float* b3 = (const float*)d_in[10];

    float* out   = (float*)d_out;
    float* Etot  = out;                 // [B]
    float* Ei    = out + B;             // [B,N]
    float* Force = out + B + B * N;     // [B,N,3]
    float* dE    = (float*)d_ws;        // [B,N,F]

    mlp_kernel<<<(B * N) / APB, BT, 0, stream>>>(image, W1, b1, W2, b2, W3, b3, Ei, dE);
    force_kernel<<<B * N + B, 256, 0, stream>>>(dE, dfeat, neighbor, Ei, Force, Etot);
}

// Round 17
// 44.868 us; speedup vs baseline: 1.4495x; 1.0115x over previous
//
#include <hip/hip_runtime.h>

#define B 4
#define N 1024
#define K 100
#define F 42
#define H 64

#define PAIRS (K * F)          // 4200
#define MF4   (PAIRS * 3 / 4)  // 3150 f32x4 of dfeat per atom
#define QP    (PAIRS / 4)      // 1050 quad-pairs per atom

#define APW 2                  // mlp: atoms per wave (v13 = R13 best)
#define NWV 8                  // mlp: waves per block
#define APB (APW * NWV)        // 16 atoms/block -> grid 256
#define BT  (NWV * 64)         // 512 threads
#define PW  68
#define PX  44

typedef float f32x4 __attribute__((ext_vector_type(4)));

// ---------------------------------------------------------------------------
// Kernel 1 (v13, byte-identical to R13 best): MLP fwd + input grad.
// ---------------------------------------------------------------------------
__global__ __launch_bounds__(BT) void mlp_kernel(
    const float* __restrict__ image,
    const float* __restrict__ W1, const float* __restrict__ b1,
    const float* __restrict__ W2, const float* __restrict__ b2,
    const float* __restrict__ W3, const float* __restrict__ b3,
    float* __restrict__ Ei, float* __restrict__ dE)
{
    __shared__ __align__(16) float W1s[F][PW];
    __shared__ __align__(16) float W2s[H][PW];
    __shared__ __align__(16) float xsh[APB][PX];
    __shared__ __align__(16) float h1sh[NWV][APW][H];
    __shared__ __align__(16) float g2sh[NWV][APW][H];
    __shared__ __align__(16) float g1sh[NWV][APW][H];

    const int tid  = threadIdx.x;
    const int lane = tid & 63;
    const int wv   = tid >> 6;          // 0..7
    const int a0   = blockIdx.x * APB;
    const int aw   = a0 + wv * APW;

    for (int idx = tid; idx < F * H; idx += BT)
        W1s[idx >> 6][idx & 63] = W1[idx];
    for (int idx = tid; idx < H * H; idx += BT)
        W2s[idx >> 6][idx & 63] = W2[idx];
    for (int idx = tid; idx < APB * F; idx += BT) {
        const int a = idx / F, f = idx - a * F;
        xsh[a][f] = image[(size_t)a0 * F + idx];
    }
    __syncthreads();

    float acc[APW];
    {
        const float bb = b1[lane];
        #pragma unroll
        for (int a = 0; a < APW; ++a) acc[a] = bb;
    }
    #pragma unroll
    for (int fc = 0; fc < 10; ++fc) {
        float wv4[4];
        #pragma unroll
        for (int t = 0; t < 4; ++t) wv4[t] = W1s[4 * fc + t][lane];
        #pragma unroll
        for (int a = 0; a < APW; ++a) {
            const f32x4 xv = *(const f32x4*)&xsh[wv * APW + a][4 * fc];
            #pragma unroll
            for (int t = 0; t < 4; ++t) acc[a] = fmaf(xv[t], wv4[t], acc[a]);
        }
    }
    #pragma unroll
    for (int f = 40; f < F; ++f) {
        const float w = W1s[f][lane];
        #pragma unroll
        for (int a = 0; a < APW; ++a) acc[a] = fmaf(xsh[wv * APW + a][f], w, acc[a]);
    }
    float h1l[APW];
    #pragma unroll
    for (int a = 0; a < APW; ++a) {
        h1l[a] = tanhf(acc[a]);
        h1sh[wv][a][lane] = h1l[a];
    }
    __builtin_amdgcn_wave_barrier();

    {
        const float bb = b2[lane];
        #pragma unroll
        for (int a = 0; a < APW; ++a) acc[a] = bb;
    }
    #pragma unroll
    for (int jc = 0; jc < H / 4; ++jc) {
        float wv4[4];
        #pragma unroll
        for (int t = 0; t < 4; ++t) wv4[t] = W2s[4 * jc + t][lane];
        #pragma unroll
        for (int a = 0; a < APW; ++a) {
            const f32x4 hv = *(const f32x4*)&h1sh[wv][a][4 * jc];
            #pragma unroll
            for (int t = 0; t < 4; ++t) acc[a] = fmaf(hv[t], wv4[t], acc[a]);
        }
    }
    const float w3    = W3[lane];
    const float bias3 = b3[0];
    #pragma unroll
    for (int a = 0; a < APW; ++a) {
        const float h2 = tanhf(acc[a]);
        g2sh[wv][a][lane] = w3 * (1.0f - h2 * h2);
        float t = h2 * w3;
        #pragma unroll
        for (int off = 32; off > 0; off >>= 1) t += __shfl_down(t, off);
        if (lane == 0) Ei[aw + a] = t + bias3;
    }
    __builtin_amdgcn_wave_barrier();

    float s[APW];
    #pragma unroll
    for (int a = 0; a < APW; ++a) s[a] = 0.0f;
    #pragma unroll
    for (int ic = 0; ic < H / 4; ++ic) {
        const f32x4 wr = *(const f32x4*)&W2s[lane][4 * ic];
        #pragma unroll
        for (int a = 0; a < APW; ++a) {
            const f32x4 gv = *(const f32x4*)&g2sh[wv][a][4 * ic];
            #pragma unroll
            for (int t = 0; t < 4; ++t) s[a] = fmaf(wr[t], gv[t], s[a]);
        }
    }
    #pragma unroll
    for (int a = 0; a < APW; ++a)
        g1sh[wv][a][lane] = s[a] * (1.0f - h1l[a] * h1l[a]);
    __builtin_amdgcn_wave_barrier();

    if (lane < F) {
        float dx[APW];
        #pragma unroll
        for (int a = 0; a < APW; ++a) dx[a] = 0.0f;
        #pragma unroll
        for (int ic = 0; ic < H / 4; ++ic) {
            const f32x4 wr = *(const f32x4*)&W1s[lane][4 * ic];
            #pragma unroll
            for (int a = 0; a < APW; ++a) {
                const f32x4 gv = *(const f32x4*)&g1sh[wv][a][4 * ic];
                #pragma unroll
                for (int t = 0; t < 4; ++t) dx[a] = fmaf(wr[t], gv[t], dx[a]);
            }
        }
        #pragma unroll
        for (int a = 0; a < APW; ++a)
            dE[(size_t)(aw + a) * F + lane] = dx[a];
    }
}

// gather the 4 dE values for quad-pair p4 into 4 named registers.
// pp >= PAIRS guarded (tail slice) -> 0.
__device__ __forceinline__ void gather4(const float* __restrict__ dEb,
                                        const int* __restrict__ nsh,
                                        int p4, float e[4])
{
    const int p = 4 * p4;
    #pragma unroll
    for (int q = 0; q < 4; ++q) {
        const int pp = p + q;
        const int k  = pp / F;             // magic-mul const div
        const int f  = pp - k * F;
        const int nb = (pp < PAIRS) ? nsh[k] : 0;
        e[q] = (nb > 0) ? dEb[(nb - 1) * F + f] : 0.0f;
    }
}

// ---------------------------------------------------------------------------
// Kernel 2 (v16): Force — R9 structure with the dE gather software-pipelined
// ONE iteration ahead in registers (ec/en, static indices): gather latency
// hides under the dwordx4 stream instead of stalling each iteration's FMAs.
// unroll 1 preserved (R8 lesson: no VGPR balloon). + Etot tail blocks.
// ---------------------------------------------------------------------------
__global__ __launch_bounds__(256) void force_kernel(
    const float* __restrict__ dE, const float* __restrict__ dfeat,
    const int* __restrict__ neighbor, const float* __restrict__ Ei,
    float* __restrict__ force, float* __restrict__ Etot)
{
    __shared__ int   nsh[K];
    __shared__ float red[4][3];

    const int tid  = threadIdx.x;
    const int bid  = blockIdx.x;
    const int lane = tid & 63, wave = tid >> 6;

    if (bid >= B * N) {                    // ---- Etot tail blocks ----
        const int b = bid - B * N;
        float s = 0.0f;
        for (int i = tid; i < N; i += 256) s += Ei[b * N + i];
        #pragma unroll
        for (int off = 32; off > 0; off >>= 1) s += __shfl_down(s, off);
        if (lane == 0) red[wave][0] = s;
        __syncthreads();
        if (tid == 0)
            Etot[b] = (red[0][0] + red[1][0]) + (red[2][0] + red[3][0]);
        return;
    }

    const int bn = bid;
    const int b  = bn >> 10;               // N = 1024

    if (tid < K) nsh[tid] = neighbor[bn * K + tid];
    __syncthreads();

    const f32x4* df4 = (const f32x4*)dfeat + (size_t)bn * MF4;
    const float* dEb = dE + (size_t)b * (N * F);

    float fx = 0.0f, fy = 0.0f, fz = 0.0f;

    float ec[4], en[4];
    gather4(dEb, nsh, tid, ec);            // slice 0

    #pragma unroll 1
    for (int it = 0; it < 4; ++it) {       // full iters: quad-pairs 0..1023
        const int p4 = it * 256 + tid;
        const f32x4 d0 = df4[3 * p4 + 0];
        const f32x4 d1 = df4[3 * p4 + 1];
        const f32x4 d2 = df4[3 * p4 + 2];
        gather4(dEb, nsh, p4 + 256, en);   // prefetch next slice (slice 4 = tail, guarded)
        fx = fmaf(ec[0], d0.x, fx); fy = fmaf(ec[0], d0.y, fy); fz = fmaf(ec[0], d0.z, fz);
        fx = fmaf(ec[1], d0.w, fx); fy = fmaf(ec[1], d1.x, fy); fz = fmaf(ec[1], d1.y, fz);
        fx = fmaf(ec[2], d1.z, fx); fy = fmaf(ec[2], d1.w, fy); fz = fmaf(ec[2], d2.x, fz);
        fx = fmaf(ec[3], d2.y, fx); fy = fmaf(ec[3], d2.z, fy); fz = fmaf(ec[3], d2.w, fz);
        #pragma unroll
        for (int q = 0; q < 4; ++q) ec[q] = en[q];
    }
    if (tid < QP - 1024) {                 // tail: quad-pairs 1024..1049 (ec = slice 4)
        const int p4 = 1024 + tid;
        const f32x4 d0 = df4[3 * p4 + 0];
        const f32x4 d1 = df4[3 * p4 + 1];
        const f32x4 d2 = df4[3 * p4 + 2];
        fx = fmaf(ec[0], d0.x, fx); fy = fmaf(ec[0], d0.y, fy); fz = fmaf(ec[0], d0.z, fz);
        fx = fmaf(ec[1], d0.w, fx); fy = fmaf(ec[1], d1.x, fy); fz = fmaf(ec[1], d1.y, fz);
        fx = fmaf(ec[2], d1.z, fx); fy = fmaf(ec[2], d1.w, fy); fz = fmaf(ec[2], d2.x, fz);
        fx = fmaf(ec[3], d2.y, fx); fy = fmaf(ec[3], d2.z, fy); fz = fmaf(ec[3], d2.w, fz);
    }

    #pragma unroll
    for (int off = 32; off > 0; off >>= 1) {
        fx += __shfl_down(fx, off);
        fy += __shfl_down(fy, off);
        fz += __shfl_down(fz, off);
    }
    if (lane == 0) { red[wave][0] = fx; red[wave][1] = fy; red[wave][2] = fz; }
    __syncthreads();
    if (tid == 0) {
        force[bn * 3 + 0] = (red[0][0] + red[1][0]) + (red[2][0] + red[3][0]);
        force[bn * 3 + 1] = (red[0][1] + red[1][1]) + (red[2][1] + red[3][1]);
        force[bn * 3 + 2] = (red[0][2] + red[1][2]) + (red[2][2] + red[3][2]);
    }
}

extern "C" void kernel_launch(void* const* d_in, const int* in_sizes, int n_in,
                              void* d_out, int out_size, void* d_ws, size_t ws_size,
                              hipStream_t stream)
{
    const float* image    = (const float*)d_in[0];
    const float* dfeat    = (const float*)d_in[1];
    const int*   neighbor = (const int*)d_in[2];
    // d_in[3] Egroup_weight, d_in[4] divider: unused by the reference outputs
    const float* W1 = (const float*)d_in[5];
    const float* b1 = (const float*)d_in[6];
    const float* W2 = (const float*)d_in[7];
    const float* b2 = (const float*)d_in[8];
    const float* W3 = (const float*)d_in[9];
    const float* b3 = (const float*)d_in[10];

    float* out   = (float*)d_out;
    float* Etot  = out;                 // [B]
    float* Ei    = out + B;             // [B,N]
    float* Force = out + B + B * N;     // [B,N,3]
    float* dE    = (float*)d_ws;        // [B,N,F]

    mlp_kernel<<<(B * N) / APB, BT, 0, stream>>>(image, W1, b1, W2, b2, W3, b3, Ei, dE);
    force_kernel<<<B * N + B, 256, 0, stream>>>(dE, dfeat, neighbor, Ei, Force, Etot);
}